// Round 19
// baseline (222.692 us; speedup 1.0000x reference)
//
#include <hip/hip_runtime.h>
#include <hip/hip_bf16.h>

typedef __attribute__((ext_vector_type(8))) short bf16x8;
typedef __attribute__((ext_vector_type(4))) short bf16x4;
typedef __attribute__((ext_vector_type(4))) float f32x4;

#define B_ 2
#define S_ 2048
#define D_ 1024
#define H_ 16
#define HD_ 64
#define M_ 4096
#define NEGV (-10000.0f)

#define NQ_ 4194304      // M_*D_ elems (q/k/v each)
#define NW_ 1048576      // D_*D_ elems (each W)
#define NJOBS 3072

static __device__ __forceinline__ unsigned short f2bf(float x) {
  __hip_bfloat16 h = __float2bfloat16(x);
  return *reinterpret_cast<unsigned short*>(&h);
}

static __device__ __forceinline__ float bf2f(unsigned short u) {
  unsigned int x = ((unsigned int)u) << 16;
  return __uint_as_float(x);
}

static __device__ __forceinline__ bf16x8 cvt8(const float* p) {
  float4 a = *reinterpret_cast<const float4*>(p);
  float4 b = *reinterpret_cast<const float4*>(p + 4);
  bf16x8 r;
  r[0] = (short)f2bf(a.x); r[1] = (short)f2bf(a.y);
  r[2] = (short)f2bf(a.z); r[3] = (short)f2bf(a.w);
  r[4] = (short)f2bf(b.x); r[5] = (short)f2bf(b.y);
  r[6] = (short)f2bf(b.z); r[7] = (short)f2bf(b.w);
  return r;
}

// 16B global -> LDS DMA (dest must be wave-uniform base + lane*16).
static __device__ __forceinline__ void gl_lds16(const unsigned short* g, unsigned short* l) {
#if __has_builtin(__builtin_amdgcn_global_load_lds)
  __builtin_amdgcn_global_load_lds(
      (const __attribute__((address_space(1))) unsigned int*)g,
      (__attribute__((address_space(3))) unsigned int*)l, 16, 0, 0);
#else
  *reinterpret_cast<bf16x8*>(l) = *reinterpret_cast<const bf16x8*>(g);
#endif
}

// =================== FAST PATH (needs ws >= 50.3 MB) ===================

__global__ __launch_bounds__(256) void cvt_all(const float* __restrict__ q,
                                               const float* __restrict__ k,
                                               const float* __restrict__ v,
                                               const float* __restrict__ wq,
                                               const float* __restrict__ wk,
                                               const float* __restrict__ wv,
                                               const float* __restrict__ wo,
                                               unsigned short* __restrict__ dst) {
  for (size_t c = (size_t)blockIdx.x * 256 + threadIdx.x; c < 2097152; c += (size_t)2048 * 256) {
    const size_t e = c * 8;
    const float* s;
    if (e < (size_t)NQ_)            s = q  + e;
    else if (e < (size_t)2 * NQ_)   s = k  + (e - (size_t)NQ_);
    else if (e < (size_t)3 * NQ_)   s = v  + (e - (size_t)2 * NQ_);
    else if (e < (size_t)3 * NQ_ + NW_)     s = wq + (e - (size_t)3 * NQ_);
    else if (e < (size_t)3 * NQ_ + 2 * NW_) s = wk + (e - (size_t)3 * NQ_ - NW_);
    else if (e < (size_t)3 * NQ_ + 3 * NW_) s = wv + (e - (size_t)3 * NQ_ - 2 * NW_);
    else                                    s = wo + (e - (size_t)3 * NQ_ - 3 * NW_);
    *reinterpret_cast<bf16x8*>(dst + e) = cvt8(s);
  }
}

template<bool HSPLIT>
static __device__ __forceinline__ void core_fast(const unsigned short* A,
                                                 const unsigned short* Bw,
                                                 unsigned short* Asm, unsigned short* Bsm,
                                                 int m0, int n0, f32x4 (*acc)[4]) {
  const int tid = threadIdx.x, lane = tid & 63, wid = tid >> 6;
  const int wm = wid >> 1, wn = wid & 1;
  const int l15 = lane & 15, l4 = lane >> 4;

  for (int k0 = 0; k0 < 1024; k0 += 64) {
    __syncthreads();
#pragma unroll
    for (int i = 0; i < 4; ++i) {
      const int idx = tid + 256 * i;
      const int row = idx >> 3;
      const int ce = ((idx & 7) * 8) ^ ((row & 7) << 3);   // swizzled elem col
      const unsigned short* ga;
      if constexpr (HSPLIT) {
        const int m = m0 + row, kk = k0 + ce;
        const int bb = m >> 11, s = m & 2047;
        ga = A + (((size_t)(bb * H_ + (kk >> 6)) * S_ + s) * HD_ + (kk & 63));
      } else {
        ga = A + (size_t)(m0 + row) * 1024 + k0 + ce;
      }
      gl_lds16(ga, Asm + (size_t)idx * 8);
      gl_lds16(Bw + (size_t)(n0 + row) * 1024 + k0 + ce, Bsm + (size_t)idx * 8);
    }
    __syncthreads();
#pragma unroll
    for (int kk = 0; kk < 2; ++kk) {
      bf16x8 af[4], bfr[4];
#pragma unroll
      for (int f = 0; f < 4; ++f) {
        const int ra = wm * 64 + f * 16 + l15;
        const int ca = (kk * 32 + l4 * 8) ^ ((ra & 7) << 3);
        af[f] = *reinterpret_cast<const bf16x8*>(&Asm[ra * 64 + ca]);
        const int rb = wn * 64 + f * 16 + l15;
        const int cb = (kk * 32 + l4 * 8) ^ ((rb & 7) << 3);
        bfr[f] = *reinterpret_cast<const bf16x8*>(&Bsm[rb * 64 + cb]);
      }
#pragma unroll
      for (int fm = 0; fm < 4; ++fm)
#pragma unroll
        for (int fn = 0; fn < 4; ++fn)
          acc[fm][fn] = __builtin_amdgcn_mfma_f32_16x16x32_bf16(af[fm], bfr[fn], acc[fm][fn], 0, 0, 0);
    }
  }
}

__global__ __launch_bounds__(256) void gemm_qkv_fast(const unsigned short* __restrict__ qbf,
                                                     const unsigned short* __restrict__ kbf,
                                                     const unsigned short* __restrict__ vbf,
                                                     const unsigned short* __restrict__ wbf,
                                                     unsigned short* __restrict__ Qh,
                                                     unsigned short* __restrict__ Kh,
                                                     unsigned short* __restrict__ Vt) {
  __shared__ unsigned short Asm[128 * 64];
  __shared__ unsigned short Bsm[128 * 64];
  const int z = blockIdx.z;
  const unsigned short* A  = (z == 0) ? qbf : (z == 1) ? kbf : vbf;
  const unsigned short* Bw = wbf + (size_t)z * NW_;
  const int m0 = blockIdx.y * 128, n0 = blockIdx.x * 128;
  const int lane = threadIdx.x & 63, wid = threadIdx.x >> 6;
  const int wm = wid >> 1, wn = wid & 1;
  const int l15 = lane & 15, l4 = lane >> 4;
  f32x4 acc[4][4] = {};
  core_fast<false>(A, Bw, Asm, Bsm, m0, n0, acc);

#pragma unroll
  for (int fm = 0; fm < 4; ++fm) {
#pragma unroll
    for (int fn = 0; fn < 4; ++fn) {
      const int mg0 = m0 + wm * 64 + fm * 16 + l4 * 4;
      const int ng  = n0 + wn * 64 + fn * 16 + l15;
      const int bidx = mg0 >> 11, s = mg0 & 2047;
      const int h = ng >> 6, d = ng & 63;
      if (z < 2) {
        unsigned short* C = (z == 0) ? Qh : Kh;
#pragma unroll
        for (int r = 0; r < 4; ++r)
          C[((size_t)((bidx * H_ + h) * S_ + s + r)) * HD_ + d] = f2bf(acc[fm][fn][r]);
      } else {
        ushort4 pk;
        pk.x = f2bf(acc[fm][fn][0]); pk.y = f2bf(acc[fm][fn][1]);
        pk.z = f2bf(acc[fm][fn][2]); pk.w = f2bf(acc[fm][fn][3]);
        *reinterpret_cast<ushort4*>(&Vt[((size_t)((bidx * H_ + h) * HD_ + d)) * S_ + s]) = pk;
      }
    }
  }
}

__global__ __launch_bounds__(256) void gemm_o_fast(const unsigned short* __restrict__ ctx,
                                                   const unsigned short* __restrict__ wobf,
                                                   float* __restrict__ Cout) {
  __shared__ unsigned short Asm[128 * 64];
  __shared__ unsigned short Bsm[128 * 64];
  const int m0 = blockIdx.y * 128, n0 = blockIdx.x * 128;
  const int lane = threadIdx.x & 63, wid = threadIdx.x >> 6;
  const int wm = wid >> 1, wn = wid & 1;
  const int l15 = lane & 15, l4 = lane >> 4;
  f32x4 acc[4][4] = {};
  core_fast<true>(ctx, wobf, Asm, Bsm, m0, n0, acc);

#pragma unroll
  for (int fm = 0; fm < 4; ++fm)
#pragma unroll
    for (int fn = 0; fn < 4; ++fn) {
      const int mg0 = m0 + wm * 64 + fm * 16 + l4 * 4;
      const int ng  = n0 + wn * 64 + fn * 16 + l15;
#pragma unroll
      for (int r = 0; r < 4; ++r)
        Cout[(size_t)(mg0 + r) * 1024 + ng] = acc[fm][fn][r];
    }
}

__global__ void zero_ctr(unsigned int* c) { *c = 0; }

// ============== PERSISTENT WORK-STEALING SPLIT-K ATTENTION ==============
// 3-way split-K (768-key parts, <=12 tiles/job): 96 jobs/bh x 32bh = 3072
// jobs, LPT-ordered (length-12 jobs first, causally-empty last). Grid = 2048
// persistent blocks (exactly 8/CU = 16 waves resident); each block LOOPS,
// pulling jobs via atomicAdd -> when short/empty jobs retire the block
// immediately backfills, keeping full wave depth until the end (r18: static
// schedule drained to 2-3 blocks/CU for most of runtime -> 13% occupancy).
// Output is job-slot-addressed => deterministic regardless of steal order.
// Inner tile loop identical to r18 (swapped QK^T, lane-local softmax,
// K=16 PV, XOR swizzle).
__global__ __launch_bounds__(128) void attn_split(const unsigned short* __restrict__ Qh,
                                                  const unsigned short* __restrict__ Kh,
                                                  const unsigned short* __restrict__ Vt,
                                                  const int* __restrict__ attn_mask,
                                                  const int* __restrict__ mask_future,
                                                  float* __restrict__ Pml,
                                                  unsigned short* __restrict__ Po,
                                                  unsigned int* __restrict__ ctr) {
  constexpr int KVB = 64;
  __shared__ unsigned short Ksm[64 * 64];
  __shared__ unsigned short Vsm[64 * 64];
  __shared__ int s_job, s_any;
  const int tid = threadIdx.x, lane = tid & 63, wid = tid >> 6;  // wid 0..1
  const int l15 = lane & 15, l4 = lane >> 4;
  const bool causal = (mask_future[0] != 0);

  for (;;) {
    __syncthreads();                      // Ksm/Vsm + s_job reuse safe
    if (tid == 0) s_job = (int)atomicAdd(ctr, 1u);
    __syncthreads();
    const int g = s_job;
    if (g >= NJOBS) break;
    const int bh = g & 31, j = g >> 5, b = bh >> 4;

    // ---- LPT job decode: (qt, part) ----
    int qt, p;
    if (j < 21)      { p = 0; qt = 11 + j; }
    else if (j < 30) { p = 1; qt = 2 + j; }                       // 23..31
    else if (j < 36) { const int L = 11 - ((j - 30) >> 1); p = (j - 30) & 1;
                       qt = p ? 11 + L : L - 1; }
    else if (j < 60) { const int jj = j - 36, L = 8 - jj / 3, pp = jj % 3;
                       p = pp; qt = (pp == 0) ? L - 1 : (pp == 1) ? 11 + L : 23 + L; }
    else if (j < 72) { p = 1; qt = j - 60; }
    else             { p = 2; qt = j - 72; }

    const int q0 = qt * 64;
    const int* mrow = attn_mask + b * S_;

    if (tid == 0) s_any = 0;
    __syncthreads();
    for (int i = tid; i <= q0; i += 128)
      if (mrow[i]) s_any = 1;
    __syncthreads();
    const int kb_end_full = (causal && s_any) ? (q0 + 64) : S_;
    const int kb_lo = p * 768;
    const int kb_hi = (kb_lo + 768 < kb_end_full) ? (kb_lo + 768) : kb_end_full;

    const unsigned short* Qb = Qh + (size_t)bh * S_ * HD_;
    const unsigned short* Kb = Kh + (size_t)bh * S_ * HD_;
    const unsigned short* Vb = Vt + (size_t)bh * HD_ * S_;

    float m_run[2] = {-1e30f, -1e30f}, l_run[2] = {0.f, 0.f};
    f32x4 o[2][4] = {};

    if (kb_lo < kb_hi) {
      int qrow[2];
      bf16x8 qf0[2], qf1[2];
#pragma unroll
      for (int f = 0; f < 2; ++f) {
        qrow[f] = q0 + wid * 32 + f * 16 + l15;
        qf0[f] = *reinterpret_cast<const bf16x8*>(&Qb[(size_t)qrow[f] * HD_ + l4 * 8]);
        qf1[f] = *reinterpret_cast<const bf16x8*>(&Qb[(size_t)qrow[f] * HD_ + 32 + l4 * 8]);
      }

      bf16x8 kreg[4], vreg[4];
#pragma unroll
      for (int jj = 0; jj < 4; ++jj) {
        const int idx = tid + 128 * jj;
        const int row = idx >> 3;
        const int ce = ((idx & 7) * 8) ^ ((row & 7) << 3);
        kreg[jj] = *reinterpret_cast<const bf16x8*>(&Kb[(size_t)(kb_lo + row) * HD_ + ce]);
        vreg[jj] = *reinterpret_cast<const bf16x8*>(&Vb[(size_t)row * S_ + kb_lo + ce]);
      }

      for (int kb = kb_lo; kb < kb_hi; kb += KVB) {
        __syncthreads();
#pragma unroll
        for (int jj = 0; jj < 4; ++jj) {
          const int idx = tid + 128 * jj;
          *reinterpret_cast<bf16x8*>(&Ksm[idx * 8]) = kreg[jj];
          *reinterpret_cast<bf16x8*>(&Vsm[idx * 8]) = vreg[jj];
        }
        __syncthreads();

        if (kb + KVB < kb_hi) {
          const int kn = kb + KVB;
#pragma unroll
          for (int jj = 0; jj < 4; ++jj) {
            const int idx = tid + 128 * jj;
            const int row = idx >> 3;
            const int ce = ((idx & 7) * 8) ^ ((row & 7) << 3);
            kreg[jj] = *reinterpret_cast<const bf16x8*>(&Kb[(size_t)(kn + row) * HD_ + ce]);
            vreg[jj] = *reinterpret_cast<const bf16x8*>(&Vb[(size_t)row * S_ + kn + ce]);
          }
        }

        int4 mk4[4];
#pragma unroll
        for (int nf = 0; nf < 4; ++nf)
          mk4[nf] = *reinterpret_cast<const int4*>(&mrow[kb + nf * 16 + l4 * 4]);

#pragma unroll
        for (int f = 0; f < 2; ++f) {
          f32x4 sc[4];
#pragma unroll
          for (int nf = 0; nf < 4; ++nf) {
            const int ra = nf * 16 + l15, sw = (ra & 7) << 3;
            bf16x8 kf0 = *reinterpret_cast<const bf16x8*>(&Ksm[ra * 64 + ((l4 * 8) ^ sw)]);
            bf16x8 kf1 = *reinterpret_cast<const bf16x8*>(&Ksm[ra * 64 + ((32 + l4 * 8) ^ sw)]);
            f32x4 z = {};
            z = __builtin_amdgcn_mfma_f32_16x16x32_bf16(kf0, qf0[f], z, 0, 0, 0);
            z = __builtin_amdgcn_mfma_f32_16x16x32_bf16(kf1, qf1[f], z, 0, 0, 0);
            sc[nf] = z;
          }

          float pp_[4][4];
          float mx = -1e30f;
#pragma unroll
          for (int nf = 0; nf < 4; ++nf) {
            const int kbase = kb + nf * 16 + l4 * 4;
#pragma unroll
            for (int r = 0; r < 4; ++r) {
              float vv = sc[nf][r] * 0.125f;
              if (causal && (kbase + r) > qrow[f]) vv += NEGV;
              const int mkr = (r == 0) ? mk4[nf].x : (r == 1) ? mk4[nf].y : (r == 2) ? mk4[nf].z : mk4[nf].w;
              if (mkr == 0) vv = NEGV;
              pp_[nf][r] = vv;
              mx = fmaxf(mx, vv);
            }
          }
          mx = fmaxf(mx, __shfl_xor(mx, 16));
          mx = fmaxf(mx, __shfl_xor(mx, 32));
          const float m_new = fmaxf(m_run[f], mx);
          const float scale = __expf(m_run[f] - m_new);
          float s_loc = 0.f;
#pragma unroll
          for (int nf = 0; nf < 4; ++nf)
#pragma unroll
            for (int r = 0; r < 4; ++r) {
              float e = __expf(pp_[nf][r] - m_new);
              pp_[nf][r] = e;
              s_loc += e;
            }
          s_loc += __shfl_xor(s_loc, 16);
          s_loc += __shfl_xor(s_loc, 32);
          l_run[f] = l_run[f] * scale + s_loc;
          m_run[f] = m_new;

          float sq[4];
#pragma unroll
          for (int r = 0; r < 4; ++r) sq[r] = __shfl(scale, l4 * 4 + r);
#pragma unroll
          for (int nf2 = 0; nf2 < 4; ++nf2)
#pragma unroll
            for (int r = 0; r < 4; ++r) o[f][nf2][r] *= sq[r];

          bf16x4 pk[4];
#pragma unroll
          for (int nf = 0; nf < 4; ++nf) {
            bf16x4 t;
            t[0] = (short)f2bf(pp_[nf][0]); t[1] = (short)f2bf(pp_[nf][1]);
            t[2] = (short)f2bf(pp_[nf][2]); t[3] = (short)f2bf(pp_[nf][3]);
            pk[nf] = t;
          }
#pragma unroll
          for (int nf2 = 0; nf2 < 4; ++nf2) {
            const int rv = nf2 * 16 + l15, swv = (rv & 7) << 3;
#pragma unroll
            for (int nf = 0; nf < 4; ++nf) {
              bf16x4 vf = *reinterpret_cast<const bf16x4*>(&Vsm[rv * 64 + ((nf * 16 + l4 * 4) ^ swv)]);
              o[f][nf2] = __builtin_amdgcn_mfma_f32_16x16x16bf16_1k(pk[nf], vf, o[f][nf2], 0, 0, 0);
            }
          }
        }
      }
    }

    // ---- write UNNORMALIZED partials for this (bh, qt, part) ----
#pragma unroll
    for (int f = 0; f < 2; ++f) {
      const int row0 = q0 + wid * 32 + f * 16;
      if (l4 == 0) {
        float* pml = &Pml[(((size_t)bh * S_ + row0 + l15) * 3 + p) * 2];
        pml[0] = m_run[f];
        pml[1] = l_run[f];
      }
#pragma unroll
      for (int nf2 = 0; nf2 < 4; ++nf2)
#pragma unroll
        for (int r = 0; r < 4; ++r) {
          const int row = row0 + l4 * 4 + r;
          Po[(((size_t)bh * S_ + row) * 3 + p) * 64 + nf2 * 16 + l15] = f2bf(o[f][nf2][r]);
        }
    }
  }
}

// merge three partials per row -> ctx (head-split, overwrites Qh).
__global__ __launch_bounds__(256) void attn_combine(const float* __restrict__ Pml,
                                                    const unsigned short* __restrict__ Po,
                                                    unsigned short* __restrict__ ctx) {
  const int t = (int)blockIdx.x * 256 + (int)threadIdx.x;  // 32*2048*64 items
  const int d = t & 63;
  const size_t rb = (size_t)(t >> 6);                      // bh*2048 + row
  const float m0v = Pml[(rb * 3 + 0) * 2], l0 = Pml[(rb * 3 + 0) * 2 + 1];
  const float m1v = Pml[(rb * 3 + 1) * 2], l1 = Pml[(rb * 3 + 1) * 2 + 1];
  const float m2v = Pml[(rb * 3 + 2) * 2], l2 = Pml[(rb * 3 + 2) * 2 + 1];
  const float ms = fmaxf(fmaxf(m0v, m1v), m2v);
  const float w0 = __expf(m0v - ms), w1 = __expf(m1v - ms), w2 = __expf(m2v - ms);
  const float L = l0 * w0 + l1 * w1 + l2 * w2;
  const float o0 = bf2f(Po[(rb * 3 + 0) * 64 + d]);
  const float o1 = bf2f(Po[(rb * 3 + 1) * 64 + d]);
  const float o2 = bf2f(Po[(rb * 3 + 2) * 64 + d]);
  ctx[rb * 64 + d] = f2bf((o0 * w0 + o1 * w1 + o2 * w2) / L);
}

// =================== FALLBACK (round-12/17, small ws) ===================

template<bool AF32, bool BF32, bool HSPLIT>
static __device__ __forceinline__ void gemm_core(const void* Av, const void* Bv,
                                                 unsigned short* Asm, unsigned short* Bsm,
                                                 int m0, int n0, f32x4 (*acc)[4]) {
  constexpr int BK = 64, LDT = 72;
  constexpr int K = 1024;
  const int tid = threadIdx.x;
  const int lane = tid & 63, wid = tid >> 6;
  const int wm = wid >> 1, wn = wid & 1;
  const int l15 = lane & 15, l4 = lane >> 4;

  for (int k0 = 0; k0 < K; k0 += BK) {
    __syncthreads();
#pragma unroll
    for (int i = 0; i < 4; ++i) {
      int idx = tid + 256 * i;
      int row = idx >> 3, k8 = (idx & 7) * 8;
      bf16x8 va, vb;
      if constexpr (AF32) {
        va = cvt8((const float*)Av + (size_t)(m0 + row) * K + k0 + k8);
      } else if constexpr (HSPLIT) {
        const int m = m0 + row, kk = k0 + k8;
        const int bb = m >> 11, s = m & 2047;
        va = *reinterpret_cast<const bf16x8*>(
            (const unsigned short*)Av +
            (((size_t)(bb * H_ + (kk >> 6)) * S_ + s) * HD_ + (kk & 63)));
      } else {
        va = *reinterpret_cast<const bf16x8*>((const unsigned short*)Av + (size_t)(m0 + row) * K + k0 + k8);
      }
      if constexpr (BF32) {
        vb = cvt8((const float*)Bv + (size_t)(n0 + row) * K + k0 + k8);
      } else {
        vb = *reinterpret_cast<const bf16x8*>((const unsigned short*)Bv + (size_t)(n0 + row) * K + k0 + k8);
      }
      *reinterpret_cast<bf16x8*>(&Asm[row * LDT + k8]) = va;
      *reinterpret_cast<bf16x8*>(&Bsm[row * LDT + k8]) = vb;
    }
    __syncthreads();
#pragma unroll
    for (int kk = 0; kk < 2; ++kk) {
      bf16x8 af[4], bfr[4];
#pragma unroll
      for (int f = 0; f < 4; ++f) {
        af[f]  = *reinterpret_cast<const bf16x8*>(&Asm[(wm * 64 + f * 16 + l15) * LDT + kk * 32 + l4 * 8]);
        bfr[f] = *reinterpret_cast<const bf16x8*>(&Bsm[(wn * 64 + f * 16 + l15) * LDT + kk * 32 + l4 * 8]);
      }
#pragma unroll
      for (int fm = 0; fm < 4; ++fm)
#pragma unroll
        for (int fn = 0; fn < 4; ++fn)
          acc[fm][fn] = __builtin_amdgcn_mfma_f32_16x16x32_bf16(af[fm], bfr[fn], acc[fm][fn], 0, 0, 0);
    }
  }
}

__global__ __launch_bounds__(256) void gemm_qkv3(const float* __restrict__ q,
                                                 const float* __restrict__ k,
                                                 const float* __restrict__ v,
                                                 const float* __restrict__ Wq,
                                                 const float* __restrict__ Wk,
                                                 const float* __restrict__ Wv,
                                                 unsigned short* __restrict__ Qh,
                                                 unsigned short* __restrict__ Kh,
                                                 unsigned short* __restrict__ Vt) {
  constexpr int LDT = 72;
  __shared__ unsigned short Asm[128 * LDT];
  __shared__ unsigned short Bsm[128 * LDT];
  const int z = blockIdx.z;
  const float* A  = (z == 0) ? q  : (z == 1) ? k  : v;
  const float* Bw = (z == 0) ? Wq : (z == 1) ? Wk : Wv;
  const int m0 = blockIdx.y * 128, n0 = blockIdx.x * 128;
  const int lane = threadIdx.x & 63, wid = threadIdx.x >> 6;
  const int wm = wid >> 1, wn = wid & 1;
  const int l15 = lane & 15, l4 = lane >> 4;
  f32x4 acc[4][4] = {};
  gemm_core<true, true, false>(A, Bw, Asm, Bsm, m0, n0, acc);

#pragma unroll
  for (int fm = 0; fm < 4; ++fm) {
#pragma unroll
    for (int fn = 0; fn < 4; ++fn) {
      const int mg0 = m0 + wm * 64 + fm * 16 + l4 * 4;
      const int ng  = n0 + wn * 64 + fn * 16 + l15;
      const int bidx = mg0 >> 11, s = mg0 & 2047;
      const int h = ng >> 6, d = ng & 63;
      if (z < 2) {
        unsigned short* C = (z == 0) ? Qh : Kh;
#pragma unroll
        for (int r = 0; r < 4; ++r)
          C[((size_t)((bidx * H_ + h) * S_ + s + r)) * HD_ + d] = f2bf(acc[fm][fn][r]);
      } else {
        ushort4 pk;
        pk.x = f2bf(acc[fm][fn][0]); pk.y = f2bf(acc[fm][fn][1]);
        pk.z = f2bf(acc[fm][fn][2]); pk.w = f2bf(acc[fm][fn][3]);
        *reinterpret_cast<ushort4*>(&Vt[((size_t)((bidx * H_ + h) * HD_ + d)) * S_ + s]) = pk;
      }
    }
  }
}

__global__ __launch_bounds__(256) void gemm_oproj(const void* __restrict__ Av,
                                                  const void* __restrict__ Bv,
                                                  float* __restrict__ Cout) {
  constexpr int LDT = 72;
  __shared__ unsigned short Asm[128 * LDT];
  __shared__ unsigned short Bsm[128 * LDT];
  const int m0 = blockIdx.y * 128, n0 = blockIdx.x * 128;
  const int lane = threadIdx.x & 63, wid = threadIdx.x >> 6;
  const int wm = wid >> 1, wn = wid & 1;
  const int l15 = lane & 15, l4 = lane >> 4;
  f32x4 acc[4][4] = {};
  gemm_core<false, true, true>(Av, Bv, Asm, Bsm, m0, n0, acc);

#pragma unroll
  for (int fm = 0; fm < 4; ++fm)
#pragma unroll
    for (int fn = 0; fn < 4; ++fn) {
      const int mg0 = m0 + wm * 64 + fm * 16 + l4 * 4;
      const int ng  = n0 + wn * 64 + fn * 16 + l15;
#pragma unroll
      for (int r = 0; r < 4; ++r)
        Cout[(size_t)(mg0 + r) * 1024 + ng] = acc[fm][fn][r];
    }
}

// r17 attention (direct ctx write) -- fallback path only.
__global__ __launch_bounds__(128) void attn_fwd(const unsigned short* Qh,
                                                const unsigned short* __restrict__ Kh,
                                                const unsigned short* __restrict__ Vt,
                                                const int* __restrict__ attn_mask,
                                                const int* __restrict__ mask_future,
                                                unsigned short* ctx) {
  constexpr int KVB = 64;
  __shared__ unsigned short Ksm[64 * 64];
  __shared__ unsigned short Vsm[64 * 64];
  __shared__ int s_any;
  const int tid = threadIdx.x, lane = tid & 63, wid = tid >> 6;
  const int l15 = lane & 15, l4 = lane >> 4;
  const int bh = blockIdx.y, b = bh >> 4;
  const int q0 = (int)((blockIdx.x + 9 * blockIdx.y) & 31) * 64;
  const bool causal = (mask_future[0] != 0);
  const int* mrow = attn_mask + b * S_;

  if (tid == 0) s_any = 0;
  __syncthreads();
  for (int i = tid; i <= q0; i += 128)
    if (mrow[i]) s_any = 1;
  __syncthreads();
  const int kb_end = (causal && s_any) ? (q0 + 64) : S_;

  const unsigned short* Qb = Qh + (size_t)bh * S_ * HD_;
  const unsigned short* Kb = Kh + (size_t)bh * S_ * HD_;
  const unsigned short* Vb = Vt + (size_t)bh * HD_ * S_;

  int qrow[2];
  bf16x8 qf0[2], qf1[2];
#pragma unroll
  for (int f = 0; f < 2; ++f) {
    qrow[f] = q0 + wid * 32 + f * 16 + l15;
    qf0[f] = *reinterpret_cast<const bf16x8*>(&Qb[(size_t)qrow[f] * HD_ + l4 * 8]);
    qf1[f] = *reinterpret_cast<const bf16x8*>(&Qb[(size_t)qrow[f] * HD_ + 32 + l4 * 8]);
  }

  float m_run[2] = {-1e30f, -1e30f}, l_run[2] = {0.f, 0.f};
  f32x4 o[2][4] = {};

  bf16x8 kreg[4], vreg[4];
#pragma unroll
  for (int j = 0; j < 4; ++j) {
    const int idx = tid + 128 * j;
    const int row = idx >> 3;
    const int ce = ((idx & 7) * 8) ^ ((row & 7) << 3);
    kreg[j] = *reinterpret_cast<const bf16x8*>(&Kb[(size_t)row * HD_ + ce]);
    vreg[j] = *reinterpret_cast<const bf16x8*>(&Vb[(size_t)row * S_ + ce]);
  }

  for (int kb = 0; kb < kb_end; kb += KVB) {
    __syncthreads();
#pragma unroll
    for (int j = 0; j < 4; ++j) {
      const int idx = tid + 128 * j;
      *reinterpret_cast<bf16x8*>(&Ksm[idx * 8]) = kreg[j];
      *reinterpret_cast<bf16x8*>(&Vsm[idx * 8]) = vreg[j];
    }
    __syncthreads();

    if (kb + KVB < kb_end) {
      const int kn = kb + KVB;
#pragma unroll
      for (int j = 0; j < 4; ++j) {
        const int idx = tid + 128 * j;
        const int row = idx >> 3;
        const int ce = ((idx & 7) * 8) ^ ((row & 7) << 3);
        kreg[j] = *reinterpret_cast<const bf16x8*>(&Kb[(size_t)(kn + row) * HD_ + ce]);
        vreg[j] = *reinterpret_cast<const bf16x8*>(&Vb[(size_t)row * S_ + kn + ce]);
      }
    }

    int4 mk4[4];
#pragma unroll
    for (int nf = 0; nf < 4; ++nf)
      mk4[nf] = *reinterpret_cast<const int4*>(&mrow[kb + nf * 16 + l4 * 4]);

#pragma unroll
    for (int f = 0; f < 2; ++f) {
      f32x4 sc[4];
#pragma unroll
      for (int nf = 0; nf < 4; ++nf) {
        const int ra = nf * 16 + l15, sw = (ra & 7) << 3;
        bf16x8 kf0 = *reinterpret_cast<const bf16x8*>(&Ksm[ra * 64 + ((l4 * 8) ^ sw)]);
        bf16x8 kf1 = *reinterpret_cast<const bf16x8*>(&Ksm[ra * 64 + ((32 + l4 * 8) ^ sw)]);
        f32x4 z = {};
        z = __builtin_amdgcn_mfma_f32_16x16x32_bf16(kf0, qf0[f], z, 0, 0, 0);
        z = __builtin_amdgcn_mfma_f32_16x16x32_bf16(kf1, qf1[f], z, 0, 0, 0);
        sc[nf] = z;
      }

      float p[4][4];
      float mx = -1e30f;
#pragma unroll
      for (int nf = 0; nf < 4; ++nf) {
        const int kbase = kb + nf * 16 + l4 * 4;
#pragma unroll
        for (int r = 0; r < 4; ++r) {
          float vv = sc[nf][r] * 0.125f;
          if (causal && (kbase + r) > qrow[f]) vv += NEGV;
          const int mkr = (r == 0) ? mk4[nf].x : (r == 1) ? mk4[nf].y : (r == 2) ? mk4[nf].z : mk4[nf].w;
          if (mkr == 0) vv = NEGV;
          p[nf][r] = vv;
          mx = fmaxf(mx, vv);
        }
      }
      mx = fmaxf(mx, __shfl_xor(mx, 16));
      mx = fmaxf(mx, __shfl_xor(mx, 32));
      const float m_new = fmaxf(m_run[f], mx);
      const float scale = __expf(m_run[f] - m_new);
      float s_loc = 0.f;
#pragma unroll
      for (int nf = 0; nf < 4; ++nf)
#pragma unroll
        for (int r = 0; r < 4; ++r) {
          float e = __expf(p[nf][r] - m_new);
          p[nf][r] = e;
          s_loc += e;
        }
      s_loc += __shfl_xor(s_loc, 16);
      s_loc += __shfl_xor(s_loc, 32);
      l_run[f] = l_run[f] * scale + s_loc;
      m_run[f] = m_new;

      float sq[4];
#pragma unroll
      for (int r = 0; r < 4; ++r) sq[r] = __shfl(scale, l4 * 4 + r);
#pragma unroll
      for (int nf2 = 0; nf2 < 4; ++nf2)
#pragma unroll
        for (int r = 0; r < 4; ++r) o[f][nf2][r] *= sq[r];

      bf16x4 pk[4];
#pragma unroll
      for (int nf = 0; nf < 4; ++nf) {
        bf16x4 t;
        t[0] = (short)f2bf(p[nf][0]); t[1] = (short)f2bf(p[nf][1]);
        t[2] = (short)f2bf(p[nf][2]); t[3] = (short)f2bf(p[nf][3]);
        pk[nf] = t;
      }
#pragma unroll
      for (int nf2 = 0; nf2 < 4; ++nf2) {
        const int rv = nf2 * 16 + l15, swv = (rv & 7) << 3;
#pragma unroll
        for (int nf = 0; nf < 4; ++nf) {
          bf16x4 vf = *reinterpret_cast<const bf16x4*>(&Vsm[rv * 64 + ((nf * 16 + l4 * 4) ^ swv)]);
          o[f][nf2] = __builtin_amdgcn_mfma_f32_16x16x16bf16_1k(pk[nf], vf, o[f][nf2], 0, 0, 0);
        }
      }
    }
  }

#pragma unroll
  for (int f = 0; f < 2; ++f) {
    const float linv = 1.f / l_run[f];
    float lq[4];
#pragma unroll
    for (int r = 0; r < 4; ++r) lq[r] = __shfl(linv, l4 * 4 + r);
#pragma unroll
    for (int nf2 = 0; nf2 < 4; ++nf2)
#pragma unroll
      for (int r = 0; r < 4; ++r) {
        const int rowg = q0 + wid * 32 + f * 16 + l4 * 4 + r;
        ctx[((size_t)bh * S_ + rowg) * HD_ + nf2 * 16 + l15] = f2bf(o[f][nf2][r] * lq[r]);
      }
  }
}

extern "C" void kernel_launch(void* const* d_in, const int* in_sizes, int n_in,
                              void* d_out, int out_size, void* d_ws, size_t ws_size,
                              hipStream_t stream) {
  const float* q = (const float*)d_in[0];
  const float* k = (const float*)d_in[1];
  const float* v = (const float*)d_in[2];
  const int* attn_mask = (const int*)d_in[3];
  const float* Wq = (const float*)d_in[4];
  const float* Wk = (const float*)d_in[5];
  const float* Wv = (const float*)d_in[6];
  const float* Wo = (const float*)d_in[7];
  const int* mask_future = (const int*)d_in[8];

  unsigned short* ws = (unsigned short*)d_ws;
  unsigned short* Vt = (unsigned short*)d_out;   // bf16 staging in f32 out buf
  float* out = (float*)d_out;
  (void)in_sizes; (void)n_in; (void)out_size;

  const size_t CVT_ELEMS = (size_t)3 * NQ_ + 4 * NW_;          // 16777216
  const size_t NEED = (CVT_ELEMS + 2 * (size_t)NQ_) * 2;        // 50331648 B

  if (ws_size >= NEED) {
    unsigned short* cvt = ws;
    unsigned short* qbf = cvt;
    unsigned short* kbf = cvt + (size_t)NQ_;
    unsigned short* vbf = cvt + (size_t)2 * NQ_;
    unsigned short* wbf = cvt + (size_t)3 * NQ_;                // Wq,Wk,Wv,Wo
    unsigned short* Qh  = cvt + CVT_ELEMS;
    unsigned short* Kh  = Qh + (size_t)NQ_;
    // Partials overlay DEAD regions (qbf/kbf/vbf + wq slot, dead after qkv):
    //   Po : 32*2048*3*64 bf16 = 3*NQ_ elems EXACTLY -> at cvt+0
    //   Pml: 32*2048*3*2 f32 = 1.57 MB -> at wq slot (2.1 MB)
    //   ctr: 4 B after Pml (still inside wq slot)
    unsigned short* Po = cvt;
    float* Pml = (float*)(cvt + (size_t)3 * NQ_);
    unsigned int* ctr = (unsigned int*)(Pml + (size_t)32 * 2048 * 3 * 2);

    cvt_all<<<2048, 256, 0, stream>>>(q, k, v, Wq, Wk, Wv, Wo, cvt);
    gemm_qkv_fast<<<dim3(8, 32, 3), 256, 0, stream>>>(qbf, kbf, vbf, wbf, Qh, Kh, Vt);
    zero_ctr<<<1, 1, 0, stream>>>(ctr);
    attn_split<<<2048, 128, 0, stream>>>(Qh, Kh, Vt, attn_mask, mask_future, Pml, Po, ctr);
    attn_combine<<<16384, 256, 0, stream>>>(Pml, Po, Qh);
    gemm_o_fast<<<dim3(8, 32), 256, 0, stream>>>(Qh, wbf + (size_t)3 * NW_, out);
  } else {
    unsigned short* Qh = ws;
    unsigned short* Kh = ws + (size_t)NQ_;
    gemm_qkv3<<<dim3(8, 32, 3), 256, 0, stream>>>(q, k, v, Wq, Wk, Wv, Qh, Kh, Vt);
    attn_fwd<<<dim3(32, 32), 128, 0, stream>>>(Qh, Kh, Vt, attn_mask, mask_future, Qh);
    gemm_oproj<<<dim3(8, 32), 256, 0, stream>>>(Qh, Wo, out);
  }
}

// Round 20
// 175.094 us; speedup vs baseline: 1.2718x; 1.2718x over previous
//
#include <hip/hip_runtime.h>
#include <hip/hip_bf16.h>

typedef __attribute__((ext_vector_type(8))) short bf16x8;
typedef __attribute__((ext_vector_type(4))) short bf16x4;
typedef __attribute__((ext_vector_type(4))) float f32x4;

#define B_ 2
#define S_ 2048
#define D_ 1024
#define H_ 16
#define HD_ 64
#define M_ 4096
#define NEGV (-10000.0f)

#define NQ_ 4194304      // M_*D_ elems (q/k/v each)
#define NW_ 1048576      // D_*D_ elems (each W)

#if __has_builtin(__builtin_amdgcn_mfma_f32_16x16x16bf16_1k)
#define HAVE_MFMA16 1
#else
#define HAVE_MFMA16 0
#endif

static __device__ __forceinline__ unsigned short f2bf(float x) {
  __hip_bfloat16 h = __float2bfloat16(x);
  return *reinterpret_cast<unsigned short*>(&h);
}

static __device__ __forceinline__ bf16x8 cvt8(const float* p) {
  float4 a = *reinterpret_cast<const float4*>(p);
  float4 b = *reinterpret_cast<const float4*>(p + 4);
  bf16x8 r;
  r[0] = (short)f2bf(a.x); r[1] = (short)f2bf(a.y);
  r[2] = (short)f2bf(a.z); r[3] = (short)f2bf(a.w);
  r[4] = (short)f2bf(b.x); r[5] = (short)f2bf(b.y);
  r[6] = (short)f2bf(b.z); r[7] = (short)f2bf(b.w);
  return r;
}

// 16B global -> LDS DMA (dest must be wave-uniform base + lane*16).
static __device__ __forceinline__ void gl_lds16(const unsigned short* g, unsigned short* l) {
#if __has_builtin(__builtin_amdgcn_global_load_lds)
  __builtin_amdgcn_global_load_lds(
      (const __attribute__((address_space(1))) unsigned int*)g,
      (__attribute__((address_space(3))) unsigned int*)l, 16, 0, 0);
#else
  *reinterpret_cast<bf16x8*>(l) = *reinterpret_cast<const bf16x8*>(g);
#endif
}

// =================== FAST PATH (needs ws >= 50.3 MB) ===================

__global__ __launch_bounds__(256) void cvt_all(const float* __restrict__ q,
                                               const float* __restrict__ k,
                                               const float* __restrict__ v,
                                               const float* __restrict__ wq,
                                               const float* __restrict__ wk,
                                               const float* __restrict__ wv,
                                               const float* __restrict__ wo,
                                               unsigned short* __restrict__ dst) {
  for (size_t c = (size_t)blockIdx.x * 256 + threadIdx.x; c < 2097152; c += (size_t)2048 * 256) {
    const size_t e = c * 8;
    const float* s;
    if (e < (size_t)NQ_)            s = q  + e;
    else if (e < (size_t)2 * NQ_)   s = k  + (e - (size_t)NQ_);
    else if (e < (size_t)3 * NQ_)   s = v  + (e - (size_t)2 * NQ_);
    else if (e < (size_t)3 * NQ_ + NW_)     s = wq + (e - (size_t)3 * NQ_);
    else if (e < (size_t)3 * NQ_ + 2 * NW_) s = wk + (e - (size_t)3 * NQ_ - NW_);
    else if (e < (size_t)3 * NQ_ + 3 * NW_) s = wv + (e - (size_t)3 * NQ_ - 2 * NW_);
    else                                    s = wo + (e - (size_t)3 * NQ_ - 3 * NW_);
    *reinterpret_cast<bf16x8*>(dst + e) = cvt8(s);
  }
}

template<bool HSPLIT>
static __device__ __forceinline__ void core_fast(const unsigned short* A,
                                                 const unsigned short* Bw,
                                                 unsigned short* Asm, unsigned short* Bsm,
                                                 int m0, int n0, f32x4 (*acc)[4]) {
  const int tid = threadIdx.x, lane = tid & 63, wid = tid >> 6;
  const int wm = wid >> 1, wn = wid & 1;
  const int l15 = lane & 15, l4 = lane >> 4;

  for (int k0 = 0; k0 < 1024; k0 += 64) {
    __syncthreads();
#pragma unroll
    for (int i = 0; i < 4; ++i) {
      const int idx = tid + 256 * i;
      const int row = idx >> 3;
      const int ce = ((idx & 7) * 8) ^ ((row & 7) << 3);   // swizzled elem col
      const unsigned short* ga;
      if constexpr (HSPLIT) {
        const int m = m0 + row, kk = k0 + ce;
        const int bb = m >> 11, s = m & 2047;
        ga = A + (((size_t)(bb * H_ + (kk >> 6)) * S_ + s) * HD_ + (kk & 63));
      } else {
        ga = A + (size_t)(m0 + row) * 1024 + k0 + ce;
      }
      gl_lds16(ga, Asm + (size_t)idx * 8);
      gl_lds16(Bw + (size_t)(n0 + row) * 1024 + k0 + ce, Bsm + (size_t)idx * 8);
    }
    __syncthreads();
#pragma unroll
    for (int kk = 0; kk < 2; ++kk) {
      bf16x8 af[4], bfr[4];
#pragma unroll
      for (int f = 0; f < 4; ++f) {
        const int ra = wm * 64 + f * 16 + l15;
        const int ca = (kk * 32 + l4 * 8) ^ ((ra & 7) << 3);
        af[f] = *reinterpret_cast<const bf16x8*>(&Asm[ra * 64 + ca]);
        const int rb = wn * 64 + f * 16 + l15;
        const int cb = (kk * 32 + l4 * 8) ^ ((rb & 7) << 3);
        bfr[f] = *reinterpret_cast<const bf16x8*>(&Bsm[rb * 64 + cb]);
      }
#pragma unroll
      for (int fm = 0; fm < 4; ++fm)
#pragma unroll
        for (int fn = 0; fn < 4; ++fn)
          acc[fm][fn] = __builtin_amdgcn_mfma_f32_16x16x32_bf16(af[fm], bfr[fn], acc[fm][fn], 0, 0, 0);
    }
  }
}

__global__ __launch_bounds__(256) void gemm_qkv_fast(const unsigned short* __restrict__ qbf,
                                                     const unsigned short* __restrict__ kbf,
                                                     const unsigned short* __restrict__ vbf,
                                                     const unsigned short* __restrict__ wbf,
                                                     unsigned short* __restrict__ Qh,
                                                     unsigned short* __restrict__ Kh,
                                                     unsigned short* __restrict__ Vt) {
  __shared__ unsigned short Asm[128 * 64];
  __shared__ unsigned short Bsm[128 * 64];
  const int z = blockIdx.z;
  const unsigned short* A  = (z == 0) ? qbf : (z == 1) ? kbf : vbf;
  const unsigned short* Bw = wbf + (size_t)z * NW_;
  const int m0 = blockIdx.y * 128, n0 = blockIdx.x * 128;
  const int lane = threadIdx.x & 63, wid = threadIdx.x >> 6;
  const int wm = wid >> 1, wn = wid & 1;
  const int l15 = lane & 15, l4 = lane >> 4;
  f32x4 acc[4][4] = {};
  core_fast<false>(A, Bw, Asm, Bsm, m0, n0, acc);

#pragma unroll
  for (int fm = 0; fm < 4; ++fm) {
#pragma unroll
    for (int fn = 0; fn < 4; ++fn) {
      const int mg0 = m0 + wm * 64 + fm * 16 + l4 * 4;
      const int ng  = n0 + wn * 64 + fn * 16 + l15;
      const int bidx = mg0 >> 11, s = mg0 & 2047;
      const int h = ng >> 6, d = ng & 63;
      if (z < 2) {
        unsigned short* C = (z == 0) ? Qh : Kh;
#pragma unroll
        for (int r = 0; r < 4; ++r)
          C[((size_t)((bidx * H_ + h) * S_ + s + r)) * HD_ + d] = f2bf(acc[fm][fn][r]);
      } else {
        ushort4 pk;
        pk.x = f2bf(acc[fm][fn][0]); pk.y = f2bf(acc[fm][fn][1]);
        pk.z = f2bf(acc[fm][fn][2]); pk.w = f2bf(acc[fm][fn][3]);
        *reinterpret_cast<ushort4*>(&Vt[((size_t)((bidx * H_ + h) * HD_ + d)) * S_ + s]) = pk;
      }
    }
  }
}

__global__ __launch_bounds__(256) void gemm_o_fast(const unsigned short* __restrict__ ctx,
                                                   const unsigned short* __restrict__ wobf,
                                                   float* __restrict__ Cout) {
  __shared__ unsigned short Asm[128 * 64];
  __shared__ unsigned short Bsm[128 * 64];
  const int m0 = blockIdx.y * 128, n0 = blockIdx.x * 128;
  const int lane = threadIdx.x & 63, wid = threadIdx.x >> 6;
  const int wm = wid >> 1, wn = wid & 1;
  const int l15 = lane & 15, l4 = lane >> 4;
  f32x4 acc[4][4] = {};
  core_fast<true>(ctx, wobf, Asm, Bsm, m0, n0, acc);

#pragma unroll
  for (int fm = 0; fm < 4; ++fm)
#pragma unroll
    for (int fn = 0; fn < 4; ++fn) {
      const int mg0 = m0 + wm * 64 + fm * 16 + l4 * 4;
      const int ng  = n0 + wn * 64 + fn * 16 + l15;
#pragma unroll
      for (int r = 0; r < 4; ++r)
        Cout[(size_t)(mg0 + r) * 1024 + ng] = acc[fm][fn][r];
    }
}

// =================== FALLBACK GEMMs (round-12) ===================

template<bool AF32, bool BF32, bool HSPLIT>
static __device__ __forceinline__ void gemm_core(const void* Av, const void* Bv,
                                                 unsigned short* Asm, unsigned short* Bsm,
                                                 int m0, int n0, f32x4 (*acc)[4]) {
  constexpr int BK = 64, LDT = 72;
  constexpr int K = 1024;
  const int tid = threadIdx.x;
  const int lane = tid & 63, wid = tid >> 6;
  const int wm = wid >> 1, wn = wid & 1;
  const int l15 = lane & 15, l4 = lane >> 4;

  for (int k0 = 0; k0 < K; k0 += BK) {
    __syncthreads();
#pragma unroll
    for (int i = 0; i < 4; ++i) {
      int idx = tid + 256 * i;
      int row = idx >> 3, k8 = (idx & 7) * 8;
      bf16x8 va, vb;
      if constexpr (AF32) {
        va = cvt8((const float*)Av + (size_t)(m0 + row) * K + k0 + k8);
      } else if constexpr (HSPLIT) {
        const int m = m0 + row, kk = k0 + k8;
        const int bb = m >> 11, s = m & 2047;
        va = *reinterpret_cast<const bf16x8*>(
            (const unsigned short*)Av +
            (((size_t)(bb * H_ + (kk >> 6)) * S_ + s) * HD_ + (kk & 63)));
      } else {
        va = *reinterpret_cast<const bf16x8*>((const unsigned short*)Av + (size_t)(m0 + row) * K + k0 + k8);
      }
      if constexpr (BF32) {
        vb = cvt8((const float*)Bv + (size_t)(n0 + row) * K + k0 + k8);
      } else {
        vb = *reinterpret_cast<const bf16x8*>((const unsigned short*)Bv + (size_t)(n0 + row) * K + k0 + k8);
      }
      *reinterpret_cast<bf16x8*>(&Asm[row * LDT + k8]) = va;
      *reinterpret_cast<bf16x8*>(&Bsm[row * LDT + k8]) = vb;
    }
    __syncthreads();
#pragma unroll
    for (int kk = 0; kk < 2; ++kk) {
      bf16x8 af[4], bfr[4];
#pragma unroll
      for (int f = 0; f < 4; ++f) {
        af[f]  = *reinterpret_cast<const bf16x8*>(&Asm[(wm * 64 + f * 16 + l15) * LDT + kk * 32 + l4 * 8]);
        bfr[f] = *reinterpret_cast<const bf16x8*>(&Bsm[(wn * 64 + f * 16 + l15) * LDT + kk * 32 + l4 * 8]);
      }
#pragma unroll
      for (int fm = 0; fm < 4; ++fm)
#pragma unroll
        for (int fn = 0; fn < 4; ++fn)
          acc[fm][fn] = __builtin_amdgcn_mfma_f32_16x16x32_bf16(af[fm], bfr[fn], acc[fm][fn], 0, 0, 0);
    }
  }
}

__global__ __launch_bounds__(256) void gemm_qkv3(const float* __restrict__ q,
                                                 const float* __restrict__ k,
                                                 const float* __restrict__ v,
                                                 const float* __restrict__ Wq,
                                                 const float* __restrict__ Wk,
                                                 const float* __restrict__ Wv,
                                                 unsigned short* __restrict__ Qh,
                                                 unsigned short* __restrict__ Kh,
                                                 unsigned short* __restrict__ Vt) {
  constexpr int LDT = 72;
  __shared__ unsigned short Asm[128 * LDT];
  __shared__ unsigned short Bsm[128 * LDT];
  const int z = blockIdx.z;
  const float* A  = (z == 0) ? q  : (z == 1) ? k  : v;
  const float* Bw = (z == 0) ? Wq : (z == 1) ? Wk : Wv;
  const int m0 = blockIdx.y * 128, n0 = blockIdx.x * 128;
  const int lane = threadIdx.x & 63, wid = threadIdx.x >> 6;
  const int wm = wid >> 1, wn = wid & 1;
  const int l15 = lane & 15, l4 = lane >> 4;
  f32x4 acc[4][4] = {};
  gemm_core<true, true, false>(A, Bw, Asm, Bsm, m0, n0, acc);

#pragma unroll
  for (int fm = 0; fm < 4; ++fm) {
#pragma unroll
    for (int fn = 0; fn < 4; ++fn) {
      const int mg0 = m0 + wm * 64 + fm * 16 + l4 * 4;
      const int ng  = n0 + wn * 64 + fn * 16 + l15;
      const int bidx = mg0 >> 11, s = mg0 & 2047;
      const int h = ng >> 6, d = ng & 63;
      if (z < 2) {
        unsigned short* C = (z == 0) ? Qh : Kh;
#pragma unroll
        for (int r = 0; r < 4; ++r)
          C[((size_t)((bidx * H_ + h) * S_ + s + r)) * HD_ + d] = f2bf(acc[fm][fn][r]);
      } else {
        ushort4 pk;
        pk.x = f2bf(acc[fm][fn][0]); pk.y = f2bf(acc[fm][fn][1]);
        pk.z = f2bf(acc[fm][fn][2]); pk.w = f2bf(acc[fm][fn][3]);
        *reinterpret_cast<ushort4*>(&Vt[((size_t)((bidx * H_ + h) * HD_ + d)) * S_ + s]) = pk;
      }
    }
  }
}

__global__ __launch_bounds__(256) void gemm_oproj(const void* __restrict__ Av,
                                                  const void* __restrict__ Bv,
                                                  float* __restrict__ Cout) {
  constexpr int LDT = 72;
  __shared__ unsigned short Asm[128 * LDT];
  __shared__ unsigned short Bsm[128 * LDT];
  const int m0 = blockIdx.y * 128, n0 = blockIdx.x * 128;
  const int lane = threadIdx.x & 63, wid = threadIdx.x >> 6;
  const int wm = wid >> 1, wn = wid & 1;
  const int l15 = lane & 15, l4 = lane >> 4;
  f32x4 acc[4][4] = {};
  gemm_core<false, true, true>(Av, Bv, Asm, Bsm, m0, n0, acc);

#pragma unroll
  for (int fm = 0; fm < 4; ++fm)
#pragma unroll
    for (int fn = 0; fn < 4; ++fn) {
      const int mg0 = m0 + wm * 64 + fm * 16 + l4 * 4;
      const int ng  = n0 + wn * 64 + fn * 16 + l15;
#pragma unroll
      for (int r = 0; r < 4; ++r)
        Cout[(size_t)(mg0 + r) * 1024 + ng] = acc[fm][fn][r];
    }
}

// ============================ ATTENTION ============================
// r17 structure (best total): 2-wave blocks, QBLK=64 (2 frags/wave), KVB=64,
// grid (32,32), (bx+9*by)&31 q0 scatter, XOR-swizzled Ksm/Vsm, swapped QK^T,
// lane-local softmax, K=16 PV.  NEW: T13 defer-max -- skip the o-rescale
// pass + m-update when no lane's tile-max exceeds m_run+8 (P bounded by e^8;
// f32 l_run + bf16 P tolerate; first tile always takes the exact path since
// m_run=-1e30).  Saves 32 mults + 8 shfl + 2 exp per skipped tile round.
__global__ __launch_bounds__(128) void attn_fwd(const unsigned short* Qh,
                                                const unsigned short* __restrict__ Kh,
                                                const unsigned short* __restrict__ Vt,
                                                const int* __restrict__ attn_mask,
                                                const int* __restrict__ mask_future,
                                                unsigned short* ctx) {
  constexpr int KVB = 64;
  __shared__ unsigned short Ksm[64 * 64];
  __shared__ unsigned short Vsm[64 * 64];
#if !HAVE_MFMA16
  __shared__ unsigned short Psm[2][16 * 72];
#endif
  __shared__ int s_any;
  const int tid = threadIdx.x, lane = tid & 63, wid = tid >> 6;  // wid 0..1
  const int l15 = lane & 15, l4 = lane >> 4;
  const int bh = blockIdx.y, b = bh >> 4;
  const int q0 = (int)((blockIdx.x + 9 * blockIdx.y) & 31) * 64;
  const bool causal = (mask_future[0] != 0);
  const int* mrow = attn_mask + b * S_;

  if (tid == 0) s_any = 0;
  __syncthreads();
  for (int i = tid; i <= q0; i += 128)
    if (mrow[i]) s_any = 1;
  __syncthreads();
  const int kb_end = (causal && s_any) ? (q0 + 64) : S_;

  const unsigned short* Qb = Qh + (size_t)bh * S_ * HD_;
  const unsigned short* Kb = Kh + (size_t)bh * S_ * HD_;
  const unsigned short* Vb = Vt + (size_t)bh * HD_ * S_;

  // two q-frags per wave: rows q0 + wid*32 + f*16 + l15
  int qrow[2];
  bf16x8 qf0[2], qf1[2];
#pragma unroll
  for (int f = 0; f < 2; ++f) {
    qrow[f] = q0 + wid * 32 + f * 16 + l15;
    qf0[f] = *reinterpret_cast<const bf16x8*>(&Qb[(size_t)qrow[f] * HD_ + l4 * 8]);
    qf1[f] = *reinterpret_cast<const bf16x8*>(&Qb[(size_t)qrow[f] * HD_ + 32 + l4 * 8]);
  }

  float m_run[2] = {-1e30f, -1e30f}, l_run[2] = {0.f, 0.f};
  f32x4 o[2][4] = {};

  // prefetch: K 64x64 + V 64x64 = 512 chunks of 8 each; 128 thr -> 4 each
  bf16x8 kreg[4], vreg[4];
#pragma unroll
  for (int j = 0; j < 4; ++j) {
    const int idx = tid + 128 * j;
    const int row = idx >> 3;
    const int ce = ((idx & 7) * 8) ^ ((row & 7) << 3);
    kreg[j] = *reinterpret_cast<const bf16x8*>(&Kb[(size_t)row * HD_ + ce]);
    vreg[j] = *reinterpret_cast<const bf16x8*>(&Vb[(size_t)row * S_ + ce]);
  }

  for (int kb = 0; kb < kb_end; kb += KVB) {
    __syncthreads();
#pragma unroll
    for (int j = 0; j < 4; ++j) {
      const int idx = tid + 128 * j;
      *reinterpret_cast<bf16x8*>(&Ksm[idx * 8]) = kreg[j];
      *reinterpret_cast<bf16x8*>(&Vsm[idx * 8]) = vreg[j];
    }
    __syncthreads();

    if (kb + KVB < kb_end) {
      const int kn = kb + KVB;
#pragma unroll
      for (int j = 0; j < 4; ++j) {
        const int idx = tid + 128 * j;
        const int row = idx >> 3;
        const int ce = ((idx & 7) * 8) ^ ((row & 7) << 3);
        kreg[j] = *reinterpret_cast<const bf16x8*>(&Kb[(size_t)(kn + row) * HD_ + ce]);
        vreg[j] = *reinterpret_cast<const bf16x8*>(&Vb[(size_t)row * S_ + kn + ce]);
      }
    }

    // per-tile mask nibble (shared by both frags)
    int4 mk4[4];
#pragma unroll
    for (int nf = 0; nf < 4; ++nf)
      mk4[nf] = *reinterpret_cast<const int4*>(&mrow[kb + nf * 16 + l4 * 4]);

#pragma unroll
    for (int f = 0; f < 2; ++f) {
      // QK^T swapped: lane holds q=l15 (row qrow[f]), keys nf*16+l4*4+r
      f32x4 sc[4];
#pragma unroll
      for (int nf = 0; nf < 4; ++nf) {
        const int ra = nf * 16 + l15, sw = (ra & 7) << 3;
        bf16x8 kf0 = *reinterpret_cast<const bf16x8*>(&Ksm[ra * 64 + ((l4 * 8) ^ sw)]);
        bf16x8 kf1 = *reinterpret_cast<const bf16x8*>(&Ksm[ra * 64 + ((32 + l4 * 8) ^ sw)]);
        f32x4 z = {};
        z = __builtin_amdgcn_mfma_f32_16x16x32_bf16(kf0, qf0[f], z, 0, 0, 0);
        z = __builtin_amdgcn_mfma_f32_16x16x32_bf16(kf1, qf1[f], z, 0, 0, 0);
        sc[nf] = z;
      }

      // lane-local masked scores + tile max
      float p[4][4];
      float mx = -1e30f;
#pragma unroll
      for (int nf = 0; nf < 4; ++nf) {
        const int kbase = kb + nf * 16 + l4 * 4;
#pragma unroll
        for (int r = 0; r < 4; ++r) {
          float vv = sc[nf][r] * 0.125f;
          if (causal && (kbase + r) > qrow[f]) vv += NEGV;
          const int mkr = (r == 0) ? mk4[nf].x : (r == 1) ? mk4[nf].y : (r == 2) ? mk4[nf].z : mk4[nf].w;
          if (mkr == 0) vv = NEGV;
          p[nf][r] = vv;
          mx = fmaxf(mx, vv);
        }
      }
      mx = fmaxf(mx, __shfl_xor(mx, 16));
      mx = fmaxf(mx, __shfl_xor(mx, 32));

      // T13 defer-max: only rescale when some lane's max grew past m_run+8
      if (__any(mx > m_run[f] + 8.0f)) {
        const float m_new = fmaxf(m_run[f], mx);
        const float scale = __expf(m_run[f] - m_new);
        l_run[f] *= scale;
        float sq[4];
#pragma unroll
        for (int r = 0; r < 4; ++r) sq[r] = __shfl(scale, l4 * 4 + r);
#pragma unroll
        for (int nf2 = 0; nf2 < 4; ++nf2)
#pragma unroll
          for (int r = 0; r < 4; ++r) o[f][nf2][r] *= sq[r];
        m_run[f] = m_new;
      }

      float s_loc = 0.f;
#pragma unroll
      for (int nf = 0; nf < 4; ++nf)
#pragma unroll
        for (int r = 0; r < 4; ++r) {
          float e = __expf(p[nf][r] - m_run[f]);
          p[nf][r] = e;
          s_loc += e;
        }
      s_loc += __shfl_xor(s_loc, 16);
      s_loc += __shfl_xor(s_loc, 32);
      l_run[f] += s_loc;

#if HAVE_MFMA16
      bf16x4 pk[4];
#pragma unroll
      for (int nf = 0; nf < 4; ++nf) {
        bf16x4 t;
        t[0] = (short)f2bf(p[nf][0]); t[1] = (short)f2bf(p[nf][1]);
        t[2] = (short)f2bf(p[nf][2]); t[3] = (short)f2bf(p[nf][3]);
        pk[nf] = t;
      }
#pragma unroll
      for (int nf2 = 0; nf2 < 4; ++nf2) {
        const int rv = nf2 * 16 + l15, swv = (rv & 7) << 3;
#pragma unroll
        for (int nf = 0; nf < 4; ++nf) {
          bf16x4 vf = *reinterpret_cast<const bf16x4*>(&Vsm[rv * 64 + ((nf * 16 + l4 * 4) ^ swv)]);
          o[f][nf2] = __builtin_amdgcn_mfma_f32_16x16x16bf16_1k(pk[nf], vf, o[f][nf2], 0, 0, 0);
        }
      }
#else
      unsigned short* Pw = &Psm[wid][0];
#pragma unroll
      for (int nf = 0; nf < 4; ++nf)
#pragma unroll
        for (int r = 0; r < 4; ++r)
          Pw[l15 * 72 + nf * 16 + l4 * 4 + r] = f2bf(p[nf][r]);
#pragma unroll
      for (int nf2 = 0; nf2 < 4; ++nf2) {
        const int rv = nf2 * 16 + l15, swv = (rv & 7) << 3;
#pragma unroll
        for (int kk = 0; kk < 2; ++kk) {
          bf16x8 pf = *reinterpret_cast<const bf16x8*>(&Pw[l15 * 72 + kk * 32 + l4 * 8]);
          bf16x8 vf = *reinterpret_cast<const bf16x8*>(&Vsm[rv * 64 + ((kk * 32 + l4 * 8) ^ swv)]);
          o[f][nf2] = __builtin_amdgcn_mfma_f32_16x16x32_bf16(pf, vf, o[f][nf2], 0, 0, 0);
        }
      }
#endif
    }
  }

#pragma unroll
  for (int f = 0; f < 2; ++f) {
    const float linv = 1.f / l_run[f];
    float lq[4];
#pragma unroll
    for (int r = 0; r < 4; ++r) lq[r] = __shfl(linv, l4 * 4 + r);
#pragma unroll
    for (int nf2 = 0; nf2 < 4; ++nf2)
#pragma unroll
      for (int r = 0; r < 4; ++r) {
        const int rowg = q0 + wid * 32 + f * 16 + l4 * 4 + r;
        ctx[((size_t)bh * S_ + rowg) * HD_ + nf2 * 16 + l15] = f2bf(o[f][nf2][r] * lq[r]);
      }
  }
}

extern "C" void kernel_launch(void* const* d_in, const int* in_sizes, int n_in,
                              void* d_out, int out_size, void* d_ws, size_t ws_size,
                              hipStream_t stream) {
  const float* q = (const float*)d_in[0];
  const float* k = (const float*)d_in[1];
  const float* v = (const float*)d_in[2];
  const int* attn_mask = (const int*)d_in[3];
  const float* Wq = (const float*)d_in[4];
  const float* Wk = (const float*)d_in[5];
  const float* Wv = (const float*)d_in[6];
  const float* Wo = (const float*)d_in[7];
  const int* mask_future = (const int*)d_in[8];

  unsigned short* ws = (unsigned short*)d_ws;
  unsigned short* Vt = (unsigned short*)d_out;   // bf16 staging in f32 out buf
  float* out = (float*)d_out;
  (void)in_sizes; (void)n_in; (void)out_size;

  const size_t CVT_ELEMS = (size_t)3 * NQ_ + 4 * NW_;          // 16777216
  const size_t NEED = (CVT_ELEMS + 2 * (size_t)NQ_) * 2;        // 50331648 B

  if (ws_size >= NEED) {
    unsigned short* cvt = ws;
    unsigned short* qbf = cvt;
    unsigned short* kbf = cvt + (size_t)NQ_;
    unsigned short* vbf = cvt + (size_t)2 * NQ_;
    unsigned short* wbf = cvt + (size_t)3 * NQ_;                // Wq,Wk,Wv,Wo
    unsigned short* Qh  = cvt + CVT_ELEMS;
    unsigned short* Kh  = Qh + (size_t)NQ_;

    cvt_all<<<2048, 256, 0, stream>>>(q, k, v, Wq, Wk, Wv, Wo, cvt);
    gemm_qkv_fast<<<dim3(8, 32, 3), 256, 0, stream>>>(qbf, kbf, vbf, wbf, Qh, Kh, Vt);
    attn_fwd<<<dim3(32, 32), 128, 0, stream>>>(Qh, Kh, Vt, attn_mask, mask_future, Qh);
    gemm_o_fast<<<dim3(8, 32), 256, 0, stream>>>(Qh, wbf + (size_t)3 * NW_, out);
  } else {
    unsigned short* Qh = ws;
    unsigned short* Kh = ws + (size_t)NQ_;
    gemm_qkv3<<<dim3(8, 32, 3), 256, 0, stream>>>(q, k, v, Wq, Wk, Wv, Qh, Kh, Vt);
    attn_fwd<<<dim3(32, 32), 128, 0, stream>>>(Qh, Kh, Vt, attn_mask, mask_future, Qh);
    gemm_oproj<<<dim3(8, 32), 256, 0, stream>>>(Qh, Wo, out);
  }
}

// Round 21
// 174.348 us; speedup vs baseline: 1.2773x; 1.0043x over previous
//
#include <hip/hip_runtime.h>
#include <hip/hip_bf16.h>

typedef __attribute__((ext_vector_type(8))) short bf16x8;
typedef __attribute__((ext_vector_type(4))) short bf16x4;
typedef __attribute__((ext_vector_type(4))) float f32x4;

#define B_ 2
#define S_ 2048
#define D_ 1024
#define H_ 16
#define HD_ 64
#define M_ 4096
#define NEGV (-10000.0f)

#define NQ_ 4194304      // M_*D_ elems (q/k/v each)
#define NW_ 1048576      // D_*D_ elems (each W)

#if __has_builtin(__builtin_amdgcn_mfma_f32_16x16x16bf16_1k)
#define HAVE_MFMA16 1
#else
#define HAVE_MFMA16 0
#endif

static __device__ __forceinline__ unsigned short f2bf(float x) {
  __hip_bfloat16 h = __float2bfloat16(x);
  return *reinterpret_cast<unsigned short*>(&h);
}

static __device__ __forceinline__ bf16x8 cvt8(const float* p) {
  float4 a = *reinterpret_cast<const float4*>(p);
  float4 b = *reinterpret_cast<const float4*>(p + 4);
  bf16x8 r;
  r[0] = (short)f2bf(a.x); r[1] = (short)f2bf(a.y);
  r[2] = (short)f2bf(a.z); r[3] = (short)f2bf(a.w);
  r[4] = (short)f2bf(b.x); r[5] = (short)f2bf(b.y);
  r[6] = (short)f2bf(b.z); r[7] = (short)f2bf(b.w);
  return r;
}

// 16B global -> LDS DMA (dest must be wave-uniform base + lane*16).
static __device__ __forceinline__ void gl_lds16(const unsigned short* g, unsigned short* l) {
#if __has_builtin(__builtin_amdgcn_global_load_lds)
  __builtin_amdgcn_global_load_lds(
      (const __attribute__((address_space(1))) unsigned int*)g,
      (__attribute__((address_space(3))) unsigned int*)l, 16, 0, 0);
#else
  *reinterpret_cast<bf16x8*>(l) = *reinterpret_cast<const bf16x8*>(g);
#endif
}

// =================== FAST PATH (needs ws >= 50.3 MB) ===================

__global__ __launch_bounds__(256) void cvt_all(const float* __restrict__ q,
                                               const float* __restrict__ k,
                                               const float* __restrict__ v,
                                               const float* __restrict__ wq,
                                               const float* __restrict__ wk,
                                               const float* __restrict__ wv,
                                               const float* __restrict__ wo,
                                               unsigned short* __restrict__ dst) {
  for (size_t c = (size_t)blockIdx.x * 256 + threadIdx.x; c < 2097152; c += (size_t)2048 * 256) {
    const size_t e = c * 8;
    const float* s;
    if (e < (size_t)NQ_)            s = q  + e;
    else if (e < (size_t)2 * NQ_)   s = k  + (e - (size_t)NQ_);
    else if (e < (size_t)3 * NQ_)   s = v  + (e - (size_t)2 * NQ_);
    else if (e < (size_t)3 * NQ_ + NW_)     s = wq + (e - (size_t)3 * NQ_);
    else if (e < (size_t)3 * NQ_ + 2 * NW_) s = wk + (e - (size_t)3 * NQ_ - NW_);
    else if (e < (size_t)3 * NQ_ + 3 * NW_) s = wv + (e - (size_t)3 * NQ_ - 2 * NW_);
    else                                    s = wo + (e - (size_t)3 * NQ_ - 3 * NW_);
    *reinterpret_cast<bf16x8*>(dst + e) = cvt8(s);
  }
}

template<bool HSPLIT>
static __device__ __forceinline__ void core_fast(const unsigned short* A,
                                                 const unsigned short* Bw,
                                                 unsigned short* Asm, unsigned short* Bsm,
                                                 int m0, int n0, f32x4 (*acc)[4]) {
  const int tid = threadIdx.x, lane = tid & 63, wid = tid >> 6;
  const int wm = wid >> 1, wn = wid & 1;
  const int l15 = lane & 15, l4 = lane >> 4;

  for (int k0 = 0; k0 < 1024; k0 += 64) {
    __syncthreads();
#pragma unroll
    for (int i = 0; i < 4; ++i) {
      const int idx = tid + 256 * i;
      const int row = idx >> 3;
      const int ce = ((idx & 7) * 8) ^ ((row & 7) << 3);   // swizzled elem col
      const unsigned short* ga;
      if constexpr (HSPLIT) {
        const int m = m0 + row, kk = k0 + ce;
        const int bb = m >> 11, s = m & 2047;
        ga = A + (((size_t)(bb * H_ + (kk >> 6)) * S_ + s) * HD_ + (kk & 63));
      } else {
        ga = A + (size_t)(m0 + row) * 1024 + k0 + ce;
      }
      gl_lds16(ga, Asm + (size_t)idx * 8);
      gl_lds16(Bw + (size_t)(n0 + row) * 1024 + k0 + ce, Bsm + (size_t)idx * 8);
    }
    __syncthreads();
#pragma unroll
    for (int kk = 0; kk < 2; ++kk) {
      bf16x8 af[4], bfr[4];
#pragma unroll
      for (int f = 0; f < 4; ++f) {
        const int ra = wm * 64 + f * 16 + l15;
        const int ca = (kk * 32 + l4 * 8) ^ ((ra & 7) << 3);
        af[f] = *reinterpret_cast<const bf16x8*>(&Asm[ra * 64 + ca]);
        const int rb = wn * 64 + f * 16 + l15;
        const int cb = (kk * 32 + l4 * 8) ^ ((rb & 7) << 3);
        bfr[f] = *reinterpret_cast<const bf16x8*>(&Bsm[rb * 64 + cb]);
      }
#pragma unroll
      for (int fm = 0; fm < 4; ++fm)
#pragma unroll
        for (int fn = 0; fn < 4; ++fn)
          acc[fm][fn] = __builtin_amdgcn_mfma_f32_16x16x32_bf16(af[fm], bfr[fn], acc[fm][fn], 0, 0, 0);
    }
  }
}

__global__ __launch_bounds__(256) void gemm_qkv_fast(const unsigned short* __restrict__ qbf,
                                                     const unsigned short* __restrict__ kbf,
                                                     const unsigned short* __restrict__ vbf,
                                                     const unsigned short* __restrict__ wbf,
                                                     unsigned short* __restrict__ Qh,
                                                     unsigned short* __restrict__ Kh,
                                                     unsigned short* __restrict__ Vt) {
  __shared__ unsigned short Asm[128 * 64];
  __shared__ unsigned short Bsm[128 * 64];
  const int z = blockIdx.z;
  const unsigned short* A  = (z == 0) ? qbf : (z == 1) ? kbf : vbf;
  const unsigned short* Bw = wbf + (size_t)z * NW_;
  const int m0 = blockIdx.y * 128, n0 = blockIdx.x * 128;
  const int lane = threadIdx.x & 63, wid = threadIdx.x >> 6;
  const int wm = wid >> 1, wn = wid & 1;
  const int l15 = lane & 15, l4 = lane >> 4;
  f32x4 acc[4][4] = {};
  core_fast<false>(A, Bw, Asm, Bsm, m0, n0, acc);

#pragma unroll
  for (int fm = 0; fm < 4; ++fm) {
#pragma unroll
    for (int fn = 0; fn < 4; ++fn) {
      const int mg0 = m0 + wm * 64 + fm * 16 + l4 * 4;
      const int ng  = n0 + wn * 64 + fn * 16 + l15;
      const int bidx = mg0 >> 11, s = mg0 & 2047;
      const int h = ng >> 6, d = ng & 63;
      if (z < 2) {
        unsigned short* C = (z == 0) ? Qh : Kh;
#pragma unroll
        for (int r = 0; r < 4; ++r)
          C[((size_t)((bidx * H_ + h) * S_ + s + r)) * HD_ + d] = f2bf(acc[fm][fn][r]);
      } else {
        ushort4 pk;
        pk.x = f2bf(acc[fm][fn][0]); pk.y = f2bf(acc[fm][fn][1]);
        pk.z = f2bf(acc[fm][fn][2]); pk.w = f2bf(acc[fm][fn][3]);
        *reinterpret_cast<ushort4*>(&Vt[((size_t)((bidx * H_ + h) * HD_ + d)) * S_ + s]) = pk;
      }
    }
  }
}

// O-proj, BN=64 tiles: grid (16,32) = 512 blocks = 2/CU (was 1/CU at BN=128;
// the 2-barrier loop needs >=2 co-resident blocks to hide the barrier drain).
// 4 waves each own 32 rows x 64 cols (2x4 frags). LDS 24 KB.
__global__ __launch_bounds__(256) void gemm_o_fast(const unsigned short* __restrict__ ctx,
                                                   const unsigned short* __restrict__ wobf,
                                                   float* __restrict__ Cout) {
  __shared__ unsigned short Asm[128 * 64];
  __shared__ unsigned short Bsm[64 * 64];
  const int m0 = blockIdx.y * 128, n0 = blockIdx.x * 64;
  const int tid = threadIdx.x;
  const int lane = tid & 63, wid = tid >> 6;   // wid 0..3 = row band
  const int l15 = lane & 15, l4 = lane >> 4;
  f32x4 acc[2][4] = {};

  for (int k0 = 0; k0 < 1024; k0 += 64) {
    __syncthreads();
#pragma unroll
    for (int i = 0; i < 4; ++i) {             // A: 128x64 = 1024 chunks
      const int idx = tid + 256 * i;
      const int row = idx >> 3;
      const int ce = ((idx & 7) * 8) ^ ((row & 7) << 3);
      const int m = m0 + row, kk = k0 + ce;
      const int bb = m >> 11, s = m & 2047;
      gl_lds16(ctx + (((size_t)(bb * H_ + (kk >> 6)) * S_ + s) * HD_ + (kk & 63)),
               Asm + (size_t)idx * 8);
    }
#pragma unroll
    for (int i = 0; i < 2; ++i) {             // B: 64x64 = 512 chunks
      const int idx = tid + 256 * i;
      const int row = idx >> 3;
      const int ce = ((idx & 7) * 8) ^ ((row & 7) << 3);
      gl_lds16(wobf + (size_t)(n0 + row) * 1024 + k0 + ce, Bsm + (size_t)idx * 8);
    }
    __syncthreads();
#pragma unroll
    for (int kk = 0; kk < 2; ++kk) {
      bf16x8 af[2], bfr[4];
#pragma unroll
      for (int f = 0; f < 2; ++f) {
        const int ra = wid * 32 + f * 16 + l15;
        const int ca = (kk * 32 + l4 * 8) ^ ((ra & 7) << 3);
        af[f] = *reinterpret_cast<const bf16x8*>(&Asm[ra * 64 + ca]);
      }
#pragma unroll
      for (int fn = 0; fn < 4; ++fn) {
        const int rb = fn * 16 + l15;
        const int cb = (kk * 32 + l4 * 8) ^ ((rb & 7) << 3);
        bfr[fn] = *reinterpret_cast<const bf16x8*>(&Bsm[rb * 64 + cb]);
      }
#pragma unroll
      for (int f = 0; f < 2; ++f)
#pragma unroll
        for (int fn = 0; fn < 4; ++fn)
          acc[f][fn] = __builtin_amdgcn_mfma_f32_16x16x32_bf16(af[f], bfr[fn], acc[f][fn], 0, 0, 0);
    }
  }

#pragma unroll
  for (int f = 0; f < 2; ++f)
#pragma unroll
    for (int fn = 0; fn < 4; ++fn) {
      const int mg0 = m0 + wid * 32 + f * 16 + l4 * 4;
      const int ng  = n0 + fn * 16 + l15;
#pragma unroll
      for (int r = 0; r < 4; ++r)
        Cout[(size_t)(mg0 + r) * 1024 + ng] = acc[f][fn][r];
    }
}

// =================== FALLBACK GEMMs (round-12) ===================

template<bool AF32, bool BF32, bool HSPLIT>
static __device__ __forceinline__ void gemm_core(const void* Av, const void* Bv,
                                                 unsigned short* Asm, unsigned short* Bsm,
                                                 int m0, int n0, f32x4 (*acc)[4]) {
  constexpr int BK = 64, LDT = 72;
  constexpr int K = 1024;
  const int tid = threadIdx.x;
  const int lane = tid & 63, wid = tid >> 6;
  const int wm = wid >> 1, wn = wid & 1;
  const int l15 = lane & 15, l4 = lane >> 4;

  for (int k0 = 0; k0 < K; k0 += BK) {
    __syncthreads();
#pragma unroll
    for (int i = 0; i < 4; ++i) {
      int idx = tid + 256 * i;
      int row = idx >> 3, k8 = (idx & 7) * 8;
      bf16x8 va, vb;
      if constexpr (AF32) {
        va = cvt8((const float*)Av + (size_t)(m0 + row) * K + k0 + k8);
      } else if constexpr (HSPLIT) {
        const int m = m0 + row, kk = k0 + k8;
        const int bb = m >> 11, s = m & 2047;
        va = *reinterpret_cast<const bf16x8*>(
            (const unsigned short*)Av +
            (((size_t)(bb * H_ + (kk >> 6)) * S_ + s) * HD_ + (kk & 63)));
      } else {
        va = *reinterpret_cast<const bf16x8*>((const unsigned short*)Av + (size_t)(m0 + row) * K + k0 + k8);
      }
      if constexpr (BF32) {
        vb = cvt8((const float*)Bv + (size_t)(n0 + row) * K + k0 + k8);
      } else {
        vb = *reinterpret_cast<const bf16x8*>((const unsigned short*)Bv + (size_t)(n0 + row) * K + k0 + k8);
      }
      *reinterpret_cast<bf16x8*>(&Asm[row * LDT + k8]) = va;
      *reinterpret_cast<bf16x8*>(&Bsm[row * LDT + k8]) = vb;
    }
    __syncthreads();
#pragma unroll
    for (int kk = 0; kk < 2; ++kk) {
      bf16x8 af[4], bfr[4];
#pragma unroll
      for (int f = 0; f < 4; ++f) {
        af[f]  = *reinterpret_cast<const bf16x8*>(&Asm[(wm * 64 + f * 16 + l15) * LDT + kk * 32 + l4 * 8]);
        bfr[f] = *reinterpret_cast<const bf16x8*>(&Bsm[(wn * 64 + f * 16 + l15) * LDT + kk * 32 + l4 * 8]);
      }
#pragma unroll
      for (int fm = 0; fm < 4; ++fm)
#pragma unroll
        for (int fn = 0; fn < 4; ++fn)
          acc[fm][fn] = __builtin_amdgcn_mfma_f32_16x16x32_bf16(af[fm], bfr[fn], acc[fm][fn], 0, 0, 0);
    }
  }
}

__global__ __launch_bounds__(256) void gemm_qkv3(const float* __restrict__ q,
                                                 const float* __restrict__ k,
                                                 const float* __restrict__ v,
                                                 const float* __restrict__ Wq,
                                                 const float* __restrict__ Wk,
                                                 const float* __restrict__ Wv,
                                                 unsigned short* __restrict__ Qh,
                                                 unsigned short* __restrict__ Kh,
                                                 unsigned short* __restrict__ Vt) {
  constexpr int LDT = 72;
  __shared__ unsigned short Asm[128 * LDT];
  __shared__ unsigned short Bsm[128 * LDT];
  const int z = blockIdx.z;
  const float* A  = (z == 0) ? q  : (z == 1) ? k  : v;
  const float* Bw = (z == 0) ? Wq : (z == 1) ? Wk : Wv;
  const int m0 = blockIdx.y * 128, n0 = blockIdx.x * 128;
  const int lane = threadIdx.x & 63, wid = threadIdx.x >> 6;
  const int wm = wid >> 1, wn = wid & 1;
  const int l15 = lane & 15, l4 = lane >> 4;
  f32x4 acc[4][4] = {};
  gemm_core<true, true, false>(A, Bw, Asm, Bsm, m0, n0, acc);

#pragma unroll
  for (int fm = 0; fm < 4; ++fm) {
#pragma unroll
    for (int fn = 0; fn < 4; ++fn) {
      const int mg0 = m0 + wm * 64 + fm * 16 + l4 * 4;
      const int ng  = n0 + wn * 64 + fn * 16 + l15;
      const int bidx = mg0 >> 11, s = mg0 & 2047;
      const int h = ng >> 6, d = ng & 63;
      if (z < 2) {
        unsigned short* C = (z == 0) ? Qh : Kh;
#pragma unroll
        for (int r = 0; r < 4; ++r)
          C[((size_t)((bidx * H_ + h) * S_ + s + r)) * HD_ + d] = f2bf(acc[fm][fn][r]);
      } else {
        ushort4 pk;
        pk.x = f2bf(acc[fm][fn][0]); pk.y = f2bf(acc[fm][fn][1]);
        pk.z = f2bf(acc[fm][fn][2]); pk.w = f2bf(acc[fm][fn][3]);
        *reinterpret_cast<ushort4*>(&Vt[((size_t)((bidx * H_ + h) * HD_ + d)) * S_ + s]) = pk;
      }
    }
  }
}

__global__ __launch_bounds__(256) void gemm_oproj(const void* __restrict__ Av,
                                                  const void* __restrict__ Bv,
                                                  float* __restrict__ Cout) {
  constexpr int LDT = 72;
  __shared__ unsigned short Asm[128 * LDT];
  __shared__ unsigned short Bsm[128 * LDT];
  const int m0 = blockIdx.y * 128, n0 = blockIdx.x * 128;
  const int lane = threadIdx.x & 63, wid = threadIdx.x >> 6;
  const int wm = wid >> 1, wn = wid & 1;
  const int l15 = lane & 15, l4 = lane >> 4;
  f32x4 acc[4][4] = {};
  gemm_core<false, true, true>(Av, Bv, Asm, Bsm, m0, n0, acc);

#pragma unroll
  for (int fm = 0; fm < 4; ++fm)
#pragma unroll
    for (int fn = 0; fn < 4; ++fn) {
      const int mg0 = m0 + wm * 64 + fm * 16 + l4 * 4;
      const int ng  = n0 + wn * 64 + fn * 16 + l15;
#pragma unroll
      for (int r = 0; r < 4; ++r)
        Cout[(size_t)(mg0 + r) * 1024 + ng] = acc[fm][fn][r];
    }
}

// ============================ ATTENTION ============================
// QBLK=128 (4-wave/256-thr blocks, each wave 2 frags = 32 rows): each staged
// 16.4 KB K/V tile now feeds 128 q-rows -> causal staging-rounds drop
// 16896 -> 8704 (the empirical cross-round law: attn time ~ rounds).
// Grid (16,32) = 512 blocks = 2/CU x 4 waves = 8 waves/CU (same residency
// as r14/r17). Co-CU pairing tile = bx ^ (15*(by>>4)) -> per-CU-pair round
// sum EXACTLY 34 (uniform), both blocks start kb=0 in phase (r15 locality
// lesson). Swapped QK^T, lane-local softmax, T13 defer-max, K=16 PV,
// XOR-swizzled Ksm/Vsm.
__global__ __launch_bounds__(256) void attn_fwd(const unsigned short* Qh,
                                                const unsigned short* __restrict__ Kh,
                                                const unsigned short* __restrict__ Vt,
                                                const int* __restrict__ attn_mask,
                                                const int* __restrict__ mask_future,
                                                unsigned short* ctx) {
  constexpr int KVB = 64;
  __shared__ unsigned short Ksm[64 * 64];
  __shared__ unsigned short Vsm[64 * 64];
  __shared__ int s_any;
  const int tid = threadIdx.x, lane = tid & 63, wid = tid >> 6;  // wid 0..3
  const int l15 = lane & 15, l4 = lane >> 4;
  const int bh = blockIdx.y, b = bh >> 4;
  const int tile = ((int)blockIdx.x ^ (15 * ((int)blockIdx.y >> 4))) & 15;
  const int q0 = tile * 128;
  const bool causal = (mask_future[0] != 0);
  const int* mrow = attn_mask + b * S_;

  if (tid == 0) s_any = 0;
  __syncthreads();
  for (int i = tid; i <= q0; i += 256)
    if (mrow[i]) s_any = 1;
  __syncthreads();
  const int kb_end = (causal && s_any) ? (q0 + 128) : S_;

  const unsigned short* Qb = Qh + (size_t)bh * S_ * HD_;
  const unsigned short* Kb = Kh + (size_t)bh * S_ * HD_;
  const unsigned short* Vb = Vt + (size_t)bh * HD_ * S_;

  // two q-frags per wave: rows q0 + wid*32 + f*16 + l15
  int qrow[2];
  bf16x8 qf0[2], qf1[2];
#pragma unroll
  for (int f = 0; f < 2; ++f) {
    qrow[f] = q0 + wid * 32 + f * 16 + l15;
    qf0[f] = *reinterpret_cast<const bf16x8*>(&Qb[(size_t)qrow[f] * HD_ + l4 * 8]);
    qf1[f] = *reinterpret_cast<const bf16x8*>(&Qb[(size_t)qrow[f] * HD_ + 32 + l4 * 8]);
  }

  float m_run[2] = {-1e30f, -1e30f}, l_run[2] = {0.f, 0.f};
  f32x4 o[2][4] = {};

  // prefetch: K 64x64 + V 64x64 = 512 chunks of 8 each; 256 thr -> 2 each
  bf16x8 kreg[2], vreg[2];
#pragma unroll
  for (int j = 0; j < 2; ++j) {
    const int idx = tid + 256 * j;
    const int row = idx >> 3;
    const int ce = ((idx & 7) * 8) ^ ((row & 7) << 3);
    kreg[j] = *reinterpret_cast<const bf16x8*>(&Kb[(size_t)row * HD_ + ce]);
    vreg[j] = *reinterpret_cast<const bf16x8*>(&Vb[(size_t)row * S_ + ce]);
  }

  for (int kb = 0; kb < kb_end; kb += KVB) {
    __syncthreads();
#pragma unroll
    for (int j = 0; j < 2; ++j) {
      const int idx = tid + 256 * j;
      *reinterpret_cast<bf16x8*>(&Ksm[idx * 8]) = kreg[j];
      *reinterpret_cast<bf16x8*>(&Vsm[idx * 8]) = vreg[j];
    }
    __syncthreads();

    if (kb + KVB < kb_end) {
      const int kn = kb + KVB;
#pragma unroll
      for (int j = 0; j < 2; ++j) {
        const int idx = tid + 256 * j;
        const int row = idx >> 3;
        const int ce = ((idx & 7) * 8) ^ ((row & 7) << 3);
        kreg[j] = *reinterpret_cast<const bf16x8*>(&Kb[(size_t)(kn + row) * HD_ + ce]);
        vreg[j] = *reinterpret_cast<const bf16x8*>(&Vb[(size_t)row * S_ + kn + ce]);
      }
    }

    // per-tile mask nibble (shared by both frags)
    int4 mk4[4];
#pragma unroll
    for (int nf = 0; nf < 4; ++nf)
      mk4[nf] = *reinterpret_cast<const int4*>(&mrow[kb + nf * 16 + l4 * 4]);

#pragma unroll
    for (int f = 0; f < 2; ++f) {
      // QK^T swapped: lane holds q=l15 (row qrow[f]), keys nf*16+l4*4+r
      f32x4 sc[4];
#pragma unroll
      for (int nf = 0; nf < 4; ++nf) {
        const int ra = nf * 16 + l15, sw = (ra & 7) << 3;
        bf16x8 kf0 = *reinterpret_cast<const bf16x8*>(&Ksm[ra * 64 + ((l4 * 8) ^ sw)]);
        bf16x8 kf1 = *reinterpret_cast<const bf16x8*>(&Ksm[ra * 64 + ((32 + l4 * 8) ^ sw)]);
        f32x4 z = {};
        z = __builtin_amdgcn_mfma_f32_16x16x32_bf16(kf0, qf0[f], z, 0, 0, 0);
        z = __builtin_amdgcn_mfma_f32_16x16x32_bf16(kf1, qf1[f], z, 0, 0, 0);
        sc[nf] = z;
      }

      // lane-local masked scores + tile max
      float p[4][4];
      float mx = -1e30f;
#pragma unroll
      for (int nf = 0; nf < 4; ++nf) {
        const int kbase = kb + nf * 16 + l4 * 4;
#pragma unroll
        for (int r = 0; r < 4; ++r) {
          float vv = sc[nf][r] * 0.125f;
          if (causal && (kbase + r) > qrow[f]) vv += NEGV;
          const int mkr = (r == 0) ? mk4[nf].x : (r == 1) ? mk4[nf].y : (r == 2) ? mk4[nf].z : mk4[nf].w;
          if (mkr == 0) vv = NEGV;
          p[nf][r] = vv;
          mx = fmaxf(mx, vv);
        }
      }
      mx = fmaxf(mx, __shfl_xor(mx, 16));
      mx = fmaxf(mx, __shfl_xor(mx, 32));

      // T13 defer-max: only rescale when some lane's max grew past m_run+8
      if (__any(mx > m_run[f] + 8.0f)) {
        const float m_new = fmaxf(m_run[f], mx);
        const float scale = __expf(m_run[f] - m_new);
        l_run[f] *= scale;
        float sq[4];
#pragma unroll
        for (int r = 0; r < 4; ++r) sq[r] = __shfl(scale, l4 * 4 + r);
#pragma unroll
        for (int nf2 = 0; nf2 < 4; ++nf2)
#pragma unroll
          for (int r = 0; r < 4; ++r) o[f][nf2][r] *= sq[r];
        m_run[f] = m_new;
      }

      float s_loc = 0.f;
#pragma unroll
      for (int nf = 0; nf < 4; ++nf)
#pragma unroll
        for (int r = 0; r < 4; ++r) {
          float e = __expf(p[nf][r] - m_run[f]);
          p[nf][r] = e;
          s_loc += e;
        }
      s_loc += __shfl_xor(s_loc, 16);
      s_loc += __shfl_xor(s_loc, 32);
      l_run[f] += s_loc;

#if HAVE_MFMA16
      bf16x4 pk[4];
#pragma unroll
      for (int nf = 0; nf < 4; ++nf) {
        bf16x4 t;
        t[0] = (short)f2bf(p[nf][0]); t[1] = (short)f2bf(p[nf][1]);
        t[2] = (short)f2bf(p[nf][2]); t[3] = (short)f2bf(p[nf][3]);
        pk[nf] = t;
      }
#pragma unroll
      for (int nf2 = 0; nf2 < 4; ++nf2) {
        const int rv = nf2 * 16 + l15, swv = (rv & 7) << 3;
#pragma unroll
        for (int nf = 0; nf < 4; ++nf) {
          bf16x4 vf = *reinterpret_cast<const bf16x4*>(&Vsm[rv * 64 + ((nf * 16 + l4 * 4) ^ swv)]);
          o[f][nf2] = __builtin_amdgcn_mfma_f32_16x16x16bf16_1k(pk[nf], vf, o[f][nf2], 0, 0, 0);
        }
      }
#else
      // (HAVE_MFMA16 holds on gfx950; K=32 PV over zero-padded halves
      //  kept minimal for compile safety)
      bf16x4 pk[4];
#pragma unroll
      for (int nf = 0; nf < 4; ++nf) {
        bf16x4 t;
        t[0] = (short)f2bf(p[nf][0]); t[1] = (short)f2bf(p[nf][1]);
        t[2] = (short)f2bf(p[nf][2]); t[3] = (short)f2bf(p[nf][3]);
        pk[nf] = t;
      }
#pragma unroll
      for (int nf2 = 0; nf2 < 4; ++nf2) {
        const int rv = nf2 * 16 + l15, swv = (rv & 7) << 3;
#pragma unroll
        for (int nf = 0; nf < 4; ++nf) {
          bf16x4 vf = *reinterpret_cast<const bf16x4*>(&Vsm[rv * 64 + ((nf * 16 + l4 * 4) ^ swv)]);
          o[f][nf2] = __builtin_amdgcn_mfma_f32_16x16x16bf16_1k(pk[nf], vf, o[f][nf2], 0, 0, 0);
        }
      }
#endif
    }
  }

#pragma unroll
  for (int f = 0; f < 2; ++f) {
    const float linv = 1.f / l_run[f];
    float lq[4];
#pragma unroll
    for (int r = 0; r < 4; ++r) lq[r] = __shfl(linv, l4 * 4 + r);
#pragma unroll
    for (int nf2 = 0; nf2 < 4; ++nf2)
#pragma unroll
      for (int r = 0; r < 4; ++r) {
        const int rowg = q0 + wid * 32 + f * 16 + l4 * 4 + r;
        ctx[((size_t)bh * S_ + rowg) * HD_ + nf2 * 16 + l15] = f2bf(o[f][nf2][r] * lq[r]);
      }
  }
}

extern "C" void kernel_launch(void* const* d_in, const int* in_sizes, int n_in,
                              void* d_out, int out_size, void* d_ws, size_t ws_size,
                              hipStream_t stream) {
  const float* q = (const float*)d_in[0];
  const float* k = (const float*)d_in[1];
  const float* v = (const float*)d_in[2];
  const int* attn_mask = (const int*)d_in[3];
  const float* Wq = (const float*)d_in[4];
  const float* Wk = (const float*)d_in[5];
  const float* Wv = (const float*)d_in[6];
  const float* Wo = (const float*)d_in[7];
  const int* mask_future = (const int*)d_in[8];

  unsigned short* ws = (unsigned short*)d_ws;
  unsigned short* Vt = (unsigned short*)d_out;   // bf16 staging in f32 out buf
  float* out = (float*)d_out;
  (void)in_sizes; (void)n_in; (void)out_size;

  const size_t CVT_ELEMS = (size_t)3 * NQ_ + 4 * NW_;          // 16777216
  const size_t NEED = (CVT_ELEMS + 2 * (size_t)NQ_) * 2;        // 50331648 B

  if (ws_size >= NEED) {
    unsigned short* cvt = ws;
    unsigned short* qbf = cvt;
    unsigned short* kbf = cvt + (size_t)NQ_;
    unsigned short* vbf = cvt + (size_t)2 * NQ_;
    unsigned short* wbf = cvt + (size_t)3 * NQ_;                // Wq,Wk,Wv,Wo
    unsigned short* Qh  = cvt + CVT_ELEMS;
    unsigned short* Kh  = Qh + (size_t)NQ_;

    cvt_all<<<2048, 256, 0, stream>>>(q, k, v, Wq, Wk, Wv, Wo, cvt);
    gemm_qkv_fast<<<dim3(8, 32, 3), 256, 0, stream>>>(qbf, kbf, vbf, wbf, Qh, Kh, Vt);
    attn_fwd<<<dim3(16, 32), 256, 0, stream>>>(Qh, Kh, Vt, attn_mask, mask_future, Qh);
    gemm_o_fast<<<dim3(16, 32), 256, 0, stream>>>(Qh, wbf + (size_t)3 * NW_, out);
  } else {
    unsigned short* Qh = ws;
    unsigned short* Kh = ws + (size_t)NQ_;
    gemm_qkv3<<<dim3(8, 32, 3), 256, 0, stream>>>(q, k, v, Wq, Wk, Wv, Qh, Kh, Vt);
    attn_fwd<<<dim3(16, 32), 256, 0, stream>>>(Qh, Kh, Vt, attn_mask, mask_future, Qh);
    gemm_oproj<<<dim3(8, 32), 256, 0, stream>>>(Qh, Wo, out);
  }
}